// Round 4
// baseline (665.803 us; speedup 1.0000x reference)
//
#include <hip/hip_runtime.h>

// Sub4BitLinear: y = X[M,K] @ W[N,K]^T, M=8192 N=4096 K=4096
// (1) x f32->bf16, (2) dequant codes->bf16 W, (3) 256x256 8-phase MFMA GEMM.

#define M_DIM 8192
#define N_DIM 4096
#define K_DIM 4096
#define BK 64
#define NKT (K_DIM / BK)   // 64 K-tiles

typedef __attribute__((ext_vector_type(8))) short short8;
typedef __attribute__((ext_vector_type(4))) float f32x4;

#define AS1 __attribute__((address_space(1)))
#define AS3 __attribute__((address_space(3)))

__device__ __forceinline__ unsigned short f2bf(float f) {
    unsigned int u = __builtin_bit_cast(unsigned int, f);
    u += 0x7fffu + ((u >> 16) & 1u);
    return (unsigned short)(u >> 16);
}

__device__ __forceinline__ void gl_lds16(const void* g, void* l) {
    __builtin_amdgcn_global_load_lds((const AS1 void*)g, (AS3 void*)l, 16, 0, 0);
}

// ---------------- kernel 1: x f32 -> bf16 ----------------
__global__ __launch_bounds__(256) void cvt_x(const float4* __restrict__ X,
                                             ushort4* __restrict__ O, int n4) {
    int stride = gridDim.x * blockDim.x;
    for (int i = blockIdx.x * blockDim.x + threadIdx.x; i < n4; i += stride) {
        float4 v = X[i];
        ushort4 o;
        o.x = f2bf(v.x); o.y = f2bf(v.y); o.z = f2bf(v.z); o.w = f2bf(v.w);
        O[i] = o;
    }
}

// ---------------- kernel 2: dequant codes -> bf16 W ----------------
__global__ __launch_bounds__(256) void dequant(const int* __restrict__ CD,
                                               const float* __restrict__ G,
                                               ushort* __restrict__ W) {
    const int o = blockIdx.x;
    __shared__ ushort gs[8];
    if (threadIdx.x < 8) gs[threadIdx.x] = f2bf(G[o * 8 + threadIdx.x]);
    __syncthreads();
    const int4* cp = (const int4*)(CD + (size_t)o * K_DIM);
    ushort4* wp = (ushort4*)(W + (size_t)o * K_DIM);
#pragma unroll
    for (int r = 0; r < 4; ++r) {
        int idx = r * 256 + threadIdx.x;
        int4 c = cp[idx];
        ushort4 w;
        w.x = gs[c.x]; w.y = gs[c.y]; w.z = gs[c.z]; w.w = gs[c.w];
        wp[idx] = w;
    }
}

// ---------------- kernel 3: 256x256 8-phase bf16 MFMA GEMM ----------------
// 512 threads = 8 waves (2M x 4N); per-wave output 128x64 = acc[8][4] frags.
// LDS: [buf][half][128 x 64] for A and B, XOR-swizzled (elem ^= (row&7)<<3).
// All 24 per-tile ds_reads issue in the tile's first phase (h0 first); no
// blanket lgkmcnt(0) -- compiler emits minimal counted waits, so read drain
// overlaps the MFMA of earlier quadrants. vmcnt(6) at phases 4/8 exactly
// drains the next buffer's four half-stages (verified by FIFO count).
__global__ __launch_bounds__(512, 1) void gemm8(const ushort* __restrict__ A,
                                                const ushort* __restrict__ B,
                                                float* __restrict__ C) {
    __shared__ ushort As[2][2][128 * 64];
    __shared__ ushort Bs[2][2][128 * 64];

    const int tid = threadIdx.x;
    const int lane = tid & 63;
    const int wid = tid >> 6;
    const int wm = wid >> 2;        // 0..1: wave's M half of the 256 tile
    const int wn = wid & 3;         // 0..3: wave's N slice
    const int bh = wn >> 1;         // B half-buffer

    // XCD-bijective block swizzle (nwg = 512, %8 == 0)
    int wg = blockIdx.x;
    wg = (wg & 7) * (gridDim.x >> 3) + (wg >> 3);
    const int ntn = N_DIM / 256;    // 16
    const int bm = (wg / ntn) * 256;
    const int bn = (wg % ntn) * 256;

    // fragment read addressing
    const int fr = lane & 15;
    const int fkc = (lane >> 4) << 3;           // 0,8,16,24
    const int swz = (fr & 7) << 3;              // XOR in elements (bits 3-5)
    const int brow_base = (wn & 1) * 64 + fr;

    // staging: chunk c = tid; row=c>>3 (+64 for 2nd instr), slot=(c&7)^(row&7)
    const int row0 = tid >> 3;                  // 0..63
    const int sl = (((tid & 7) ^ (row0 & 7)) << 3);

#define STG(GP, RB, KT, LD) do {                                                   \
        const int ks_ = (((KT) < NKT) ? (KT) : 0) * BK;                            \
        gl_lds16((GP) + (size_t)((RB) + row0) * K_DIM + ks_ + sl,                  \
                 (LD) + wid * 512);                                                \
        gl_lds16((GP) + (size_t)((RB) + row0 + 64) * K_DIM + ks_ + sl,             \
                 (LD) + 4096 + wid * 512);                                         \
    } while (0)

#define RD_A(B_, MH_)                                                              \
    _Pragma("unroll") for (int m = 0; m < 4; ++m)                                  \
    _Pragma("unroll") for (int ks = 0; ks < 2; ++ks)                               \
        fa[(MH_) * 4 + m][ks] = *(const short8*)&As[B_][wm][                       \
            (((MH_) * 64 + m * 16 + fr) * 64 + ks * 32 + fkc) ^ swz];

#define RD_B(B_, NH_)                                                              \
    _Pragma("unroll") for (int n = 0; n < 2; ++n)                                  \
    _Pragma("unroll") for (int ks = 0; ks < 2; ++ks)                               \
        fb[(NH_) * 2 + n][ks] = *(const short8*)&Bs[B_][bh][                       \
            ((brow_base + (NH_) * 32 + n * 16) * 64 + ks * 32 + fkc) ^ swz];

// ks-outer: 8 independent accumulators between dependent MFMA pairs
#define MF(MH_, NH_)                                                               \
    _Pragma("unroll") for (int ks = 0; ks < 2; ++ks)                               \
    _Pragma("unroll") for (int m = 0; m < 4; ++m)                                  \
    _Pragma("unroll") for (int n = 0; n < 2; ++n)                                  \
        acc[(MH_) * 4 + m][(NH_) * 2 + n] = __builtin_amdgcn_mfma_f32_16x16x32_bf16( \
            fa[(MH_) * 4 + m][ks], fb[(NH_) * 2 + n][ks],                          \
            acc[(MH_) * 4 + m][(NH_) * 2 + n], 0, 0, 0);

#define PH_MID                                                                     \
    __builtin_amdgcn_s_barrier();                                                  \
    __builtin_amdgcn_sched_barrier(0);                                             \
    __builtin_amdgcn_s_setprio(1);

#define PH_END                                                                     \
    __builtin_amdgcn_s_setprio(0);                                                 \
    __builtin_amdgcn_sched_barrier(0);                                             \
    __builtin_amdgcn_s_barrier();

#define PH_ENDW                                                                    \
    __builtin_amdgcn_s_setprio(0);                                                 \
    __builtin_amdgcn_sched_barrier(0);                                             \
    asm volatile("s_waitcnt vmcnt(6)" ::: "memory");                               \
    __builtin_amdgcn_s_barrier();

    f32x4 acc[8][4] = {};
    short8 fa[8][2];
    short8 fb[4][2];

    // prologue: tile0 {A0,A1,B0,B1}; tile1 {B0,B1,A0} (steady-state order).
    STG(A, bm,       0, &As[0][0][0]);
    STG(A, bm + 128, 0, &As[0][1][0]);
    STG(B, bn,       0, &Bs[0][0][0]);
    STG(B, bn + 128, 0, &Bs[0][1][0]);
    STG(B, bn,       1, &Bs[1][0][0]);
    STG(B, bn + 128, 1, &Bs[1][1][0]);
    STG(A, bm,       1, &As[1][0][0]);
    asm volatile("s_waitcnt vmcnt(6)" ::: "memory");
    __builtin_amdgcn_s_barrier();

    for (int j = 0; j < NKT / 2; ++j) {
        const int o = 2 * j + 1, e2 = 2 * j + 2, o2 = 2 * j + 3;
        // p1: issue ALL tile-e reads (A-h0, B-h0, B-h1, A-h1); stage o.A1
        RD_A(0, 0) RD_B(0, 0) RD_B(0, 1) RD_A(0, 1)
        STG(A, bm + 128, o, &As[1][1][0]);
        PH_MID MF(0, 0) PH_END
        // p2
        PH_MID MF(0, 1) PH_END
        // p3: stage e2.B0
        STG(B, bn, e2, &Bs[0][0][0]);
        PH_MID MF(1, 0) PH_END
        // p4: stage e2.B1, e2.A0; vmcnt(6) -> tile o fully resident
        STG(B, bn + 128, e2, &Bs[0][1][0]);
        STG(A, bm, e2, &As[0][0][0]);
        PH_MID MF(1, 1) PH_ENDW
        // p5: issue ALL tile-o reads; stage e2.A1
        RD_A(1, 0) RD_B(1, 0) RD_B(1, 1) RD_A(1, 1)
        STG(A, bm + 128, e2, &As[0][1][0]);
        PH_MID MF(0, 0) PH_END
        // p6
        PH_MID MF(0, 1) PH_END
        // p7: stage o2.B0
        STG(B, bn, o2, &Bs[1][0][0]);
        PH_MID MF(1, 0) PH_END
        // p8: stage o2.B1, o2.A0; vmcnt(6) -> tile e2 fully resident
        STG(B, bn + 128, o2, &Bs[1][1][0]);
        STG(A, bm, o2, &As[1][0][0]);
        PH_MID MF(1, 1) PH_ENDW
    }
    asm volatile("s_waitcnt vmcnt(0)" ::: "memory");

    // C-write: row = (lane>>4)*4 + r, col = lane&15 within each 16x16 frag
    const int crow0 = bm + wm * 128 + ((lane >> 4) << 2);
    const int ccol0 = bn + wn * 64 + (lane & 15);
#pragma unroll
    for (int mi = 0; mi < 8; ++mi)
#pragma unroll
        for (int ni = 0; ni < 4; ++ni)
#pragma unroll
            for (int r = 0; r < 4; ++r)
                C[(size_t)(crow0 + mi * 16 + r) * N_DIM + ccol0 + ni * 16] = acc[mi][ni][r];
}

// ---------------- fallback: tiled f32 GEMM with on-the-fly dequant ----------------
__global__ __launch_bounds__(256) void fb_gemm(const float* __restrict__ X,
                                               const float* __restrict__ G,
                                               const int* __restrict__ CD,
                                               float* __restrict__ Y) {
    __shared__ float xs[16][64];
    __shared__ float ws[16][64];
    const int bm = blockIdx.y << 6, bn = blockIdx.x << 6;
    const int tid = threadIdx.x;
    const int tn = tid & 15, tm = tid >> 4;
    float acc[4][4] = {};
    for (int k0 = 0; k0 < K_DIM; k0 += 16) {
#pragma unroll
        for (int r = 0; r < 4; ++r) {
            int e = r * 256 + tid;
            int mm = e >> 4, kk = e & 15;
            xs[kk][mm] = X[(size_t)(bm + mm) * K_DIM + k0 + kk];
            int code = CD[(size_t)(bn + mm) * K_DIM + k0 + kk];
            ws[kk][mm] = G[(bn + mm) * 8 + code];
        }
        __syncthreads();
#pragma unroll
        for (int kk = 0; kk < 16; ++kk)
#pragma unroll
            for (int i = 0; i < 4; ++i)
#pragma unroll
                for (int j = 0; j < 4; ++j)
                    acc[i][j] += xs[kk][tm * 4 + i] * ws[kk][tn * 4 + j];
        __syncthreads();
    }
#pragma unroll
    for (int i = 0; i < 4; ++i)
#pragma unroll
        for (int j = 0; j < 4; ++j)
            Y[(size_t)(bm + tm * 4 + i) * N_DIM + bn + tn * 4 + j] = acc[i][j];
}

extern "C" void kernel_launch(void* const* d_in, const int* in_sizes, int n_in,
                              void* d_out, int out_size, void* d_ws, size_t ws_size,
                              hipStream_t stream) {
    const float* x = (const float*)d_in[0];
    const float* qg = (const float*)d_in[1];
    const int* wc = (const int*)d_in[2];
    float* y = (float*)d_out;

    const size_t xb_elems = (size_t)M_DIM * K_DIM;
    const size_t wb_elems = (size_t)N_DIM * K_DIM;
    const size_t need = (xb_elems + wb_elems) * sizeof(ushort);

    if (ws_size >= need) {
        ushort* xb = (ushort*)d_ws;
        ushort* wb = xb + xb_elems;
        const int n4 = (int)(xb_elems / 4);
        hipLaunchKernelGGL(cvt_x, dim3(2048), dim3(256), 0, stream,
                           (const float4*)x, (ushort4*)xb, n4);
        hipLaunchKernelGGL(dequant, dim3(N_DIM), dim3(256), 0, stream, wc, qg, wb);
        const int nwg = (M_DIM / 256) * (N_DIM / 256);   // 512
        hipLaunchKernelGGL(gemm8, dim3(nwg), dim3(512), 0, stream,
                           xb, wb, y);
    } else {
        hipLaunchKernelGGL(fb_gemm, dim3(N_DIM / 64, M_DIM / 64), dim3(256), 0, stream,
                           x, qg, wc, y);
    }
}

// Round 5
// 290.919 us; speedup vs baseline: 2.2886x; 2.2886x over previous
//
#include <hip/hip_runtime.h>

// Sub4BitLinear: y = X[M,K] @ W[N,K]^T, M=8192 N=4096 K=4096
// (1) x f32->bf16, (2) dequant codes->bf16 W, (3) 256x256 8-phase MFMA GEMM.

#define M_DIM 8192
#define N_DIM 4096
#define K_DIM 4096
#define BK 64
#define NKT (K_DIM / BK)   // 64 K-tiles

typedef __attribute__((ext_vector_type(8))) short short8;
typedef __attribute__((ext_vector_type(4))) float f32x4;

#define AS1 __attribute__((address_space(1)))
#define AS3 __attribute__((address_space(3)))

__device__ __forceinline__ unsigned short f2bf(float f) {
    unsigned int u = __builtin_bit_cast(unsigned int, f);
    u += 0x7fffu + ((u >> 16) & 1u);
    return (unsigned short)(u >> 16);
}

__device__ __forceinline__ void gl_lds16(const void* g, void* l) {
    __builtin_amdgcn_global_load_lds((const AS1 void*)g, (AS3 void*)l, 16, 0, 0);
}

// ---------------- kernel 1: x f32 -> bf16 ----------------
__global__ __launch_bounds__(256) void cvt_x(const float4* __restrict__ X,
                                             ushort4* __restrict__ O, int n4) {
    int stride = gridDim.x * blockDim.x;
    for (int i = blockIdx.x * blockDim.x + threadIdx.x; i < n4; i += stride) {
        float4 v = X[i];
        ushort4 o;
        o.x = f2bf(v.x); o.y = f2bf(v.y); o.z = f2bf(v.z); o.w = f2bf(v.w);
        O[i] = o;
    }
}

// ---------------- kernel 2: dequant codes -> bf16 W ----------------
__global__ __launch_bounds__(256) void dequant(const int* __restrict__ CD,
                                               const float* __restrict__ G,
                                               ushort* __restrict__ W) {
    const int o = blockIdx.x;
    __shared__ ushort gs[8];
    if (threadIdx.x < 8) gs[threadIdx.x] = f2bf(G[o * 8 + threadIdx.x]);
    __syncthreads();
    const int4* cp = (const int4*)(CD + (size_t)o * K_DIM);
    ushort4* wp = (ushort4*)(W + (size_t)o * K_DIM);
#pragma unroll
    for (int r = 0; r < 4; ++r) {
        int idx = r * 256 + threadIdx.x;
        int4 c = cp[idx];
        ushort4 w;
        w.x = gs[c.x]; w.y = gs[c.y]; w.z = gs[c.z]; w.w = gs[c.w];
        wp[idx] = w;
    }
}

// ---------------- kernel 3: 256x256 8-phase bf16 MFMA GEMM ----------------
// 512 threads = 8 waves (2M x 4N); per-wave output 128x64 = acc[8][4] frags.
// LDS: [buf][half][128 x 64] A and B, XOR-swizzled (elem ^= (row&7)<<3).
// Read addressing hoisted to two lane constants (offk0/offk1) so every
// ds_read is base + compile-time offset. 1 STG per phase; vmcnt(6) at p4/p8.
__global__ __launch_bounds__(512, 2) void gemm8(const ushort* __restrict__ A,
                                                const ushort* __restrict__ B,
                                                float* __restrict__ C) {
    __shared__ ushort As[2][2][128 * 64];
    __shared__ ushort Bs[2][2][128 * 64];

    const int tid = threadIdx.x;
    const int lane = tid & 63;
    const int wid = tid >> 6;
    const int wm = wid >> 2;        // 0..1: wave's M half of the 256 tile
    const int wn = wid & 3;         // 0..3: wave's N slice
    const int bh = wn >> 1;         // B half-buffer

    // XCD-bijective block swizzle (nwg = 512, %8 == 0)
    int wg = blockIdx.x;
    wg = (wg & 7) * (gridDim.x >> 3) + (wg >> 3);
    const int ntn = N_DIM / 256;    // 16
    const int bm = (wg / ntn) * 256;
    const int bn = (wg % ntn) * 256;

    // fragment read lane constants:
    // elem = quad_off(static) + offk{ks};  offk = fr*64 + ((ks*32+fkc)^swz)
    const int fr = lane & 15;
    const int fkc = (lane >> 4) << 3;           // 0,8,16,24
    const int swz = (fr & 7) << 3;
    const int offk0 = fr * 64 + (fkc ^ (swz & 24)) + (swz & 32);
    const int offk1 = offk0 ^ 32;
    const int bwoff = (wn & 1) * 4096;          // B wave row-base (elements)

    // staging: chunk c = tid; row=c>>3 (+64 for 2nd instr), slot=(c&7)^(row&7)
    const int row0 = tid >> 3;                  // 0..63
    const int sl = (((tid & 7) ^ (row0 & 7)) << 3);

#define STG(GP, RB, KT, LD) do {                                                   \
        const int ks_ = (((KT) < NKT) ? (KT) : 0) * BK;                            \
        gl_lds16((GP) + (size_t)((RB) + row0) * K_DIM + ks_ + sl,                  \
                 (LD) + wid * 512);                                                \
        gl_lds16((GP) + (size_t)((RB) + row0 + 64) * K_DIM + ks_ + sl,             \
                 (LD) + 4096 + wid * 512);                                         \
    } while (0)

#define RD_A(B_, MH_)                                                              \
    _Pragma("unroll") for (int m = 0; m < 4; ++m) {                                \
        fa[(MH_) * 4 + m][0] = *(const short8*)&As[B_][wm][(MH_) * 4096 + m * 1024 + offk0]; \
        fa[(MH_) * 4 + m][1] = *(const short8*)&As[B_][wm][(MH_) * 4096 + m * 1024 + offk1]; \
    }

#define RD_B(B_, NH_)                                                              \
    _Pragma("unroll") for (int n = 0; n < 2; ++n) {                                \
        fb[(NH_) * 2 + n][0] = *(const short8*)&Bs[B_][bh][bwoff + (NH_) * 2048 + n * 1024 + offk0]; \
        fb[(NH_) * 2 + n][1] = *(const short8*)&Bs[B_][bh][bwoff + (NH_) * 2048 + n * 1024 + offk1]; \
    }

// ks-outer: 8 independent accumulators between dependent MFMA pairs
#define MF(MH_, NH_)                                                               \
    _Pragma("unroll") for (int ks = 0; ks < 2; ++ks)                               \
    _Pragma("unroll") for (int m = 0; m < 4; ++m)                                  \
    _Pragma("unroll") for (int n = 0; n < 2; ++n)                                  \
        acc[(MH_) * 4 + m][(NH_) * 2 + n] = __builtin_amdgcn_mfma_f32_16x16x32_bf16( \
            fa[(MH_) * 4 + m][ks], fb[(NH_) * 2 + n][ks],                          \
            acc[(MH_) * 4 + m][(NH_) * 2 + n], 0, 0, 0);

#define LGKM8 asm volatile("s_waitcnt lgkmcnt(8)" ::: "memory");

#define PH_MID                                                                     \
    __builtin_amdgcn_s_barrier();                                                  \
    asm volatile("s_waitcnt lgkmcnt(0)" ::: "memory");                             \
    __builtin_amdgcn_sched_barrier(0);                                             \
    __builtin_amdgcn_s_setprio(1);

#define PH_END                                                                     \
    __builtin_amdgcn_s_setprio(0);                                                 \
    __builtin_amdgcn_sched_barrier(0);                                             \
    __builtin_amdgcn_s_barrier();

#define PH_ENDW                                                                    \
    __builtin_amdgcn_s_setprio(0);                                                 \
    __builtin_amdgcn_sched_barrier(0);                                             \
    asm volatile("s_waitcnt vmcnt(6)" ::: "memory");                               \
    __builtin_amdgcn_s_barrier();

    f32x4 acc[8][4] = {};
    short8 fa[8][2];
    short8 fb[4][2];

    // prologue: tile0 {A0,A1,B0,B1}; tile1 {B0,B1,A0} (steady-state FIFO).
    STG(A, bm,       0, &As[0][0][0]);
    STG(A, bm + 128, 0, &As[0][1][0]);
    STG(B, bn,       0, &Bs[0][0][0]);
    STG(B, bn + 128, 0, &Bs[0][1][0]);
    STG(B, bn,       1, &Bs[1][0][0]);
    STG(B, bn + 128, 1, &Bs[1][1][0]);
    STG(A, bm,       1, &As[1][0][0]);
    asm volatile("s_waitcnt vmcnt(6)" ::: "memory");
    __builtin_amdgcn_s_barrier();

    for (int j = 0; j < NKT / 2; ++j) {
        const int o = 2 * j + 1, e2 = 2 * j + 2, o2 = 2 * j + 3;
        // p1: read e.{A-h0, B-h0}; stage o.A1
        RD_A(0, 0) RD_B(0, 0)
        STG(A, bm + 128, o, &As[1][1][0]);
        LGKM8 PH_MID MF(0, 0) PH_END
        // p2: read e.B-h1; stage e2.B0
        RD_B(0, 1)
        STG(B, bn, e2, &Bs[0][0][0]);
        PH_MID MF(0, 1) PH_END
        // p3: read e.A-h1; stage e2.B1
        RD_A(0, 1)
        STG(B, bn + 128, e2, &Bs[0][1][0]);
        PH_MID MF(1, 0) PH_END
        // p4: stage e2.A0; vmcnt(6) -> tile o fully resident
        STG(A, bm, e2, &As[0][0][0]);
        PH_MID MF(1, 1) PH_ENDW
        // p5: read o.{A-h0, B-h0}; stage e2.A1
        RD_A(1, 0) RD_B(1, 0)
        STG(A, bm + 128, e2, &As[0][1][0]);
        LGKM8 PH_MID MF(0, 0) PH_END
        // p6: read o.B-h1; stage o2.B0
        RD_B(1, 1)
        STG(B, bn, o2, &Bs[1][0][0]);
        PH_MID MF(0, 1) PH_END
        // p7: read o.A-h1; stage o2.B1
        RD_A(1, 1)
        STG(B, bn + 128, o2, &Bs[1][1][0]);
        PH_MID MF(1, 0) PH_END
        // p8: stage o2.A0; vmcnt(6) -> tile e2 fully resident
        STG(A, bm, o2, &As[1][0][0]);
        PH_MID MF(1, 1) PH_ENDW
    }
    asm volatile("s_waitcnt vmcnt(0)" ::: "memory");

    // C-write: row = (lane>>4)*4 + r, col = lane&15 within each 16x16 frag
    const int crow0 = bm + wm * 128 + ((lane >> 4) << 2);
    const int ccol0 = bn + wn * 64 + (lane & 15);
#pragma unroll
    for (int mi = 0; mi < 8; ++mi)
#pragma unroll
        for (int ni = 0; ni < 4; ++ni)
#pragma unroll
            for (int r = 0; r < 4; ++r)
                C[(size_t)(crow0 + mi * 16 + r) * N_DIM + ccol0 + ni * 16] = acc[mi][ni][r];
}

// ---------------- fallback: tiled f32 GEMM with on-the-fly dequant ----------------
__global__ __launch_bounds__(256) void fb_gemm(const float* __restrict__ X,
                                               const float* __restrict__ G,
                                               const int* __restrict__ CD,
                                               float* __restrict__ Y) {
    __shared__ float xs[16][64];
    __shared__ float ws[16][64];
    const int bm = blockIdx.y << 6, bn = blockIdx.x << 6;
    const int tid = threadIdx.x;
    const int tn = tid & 15, tm = tid >> 4;
    float acc[4][4] = {};
    for (int k0 = 0; k0 < K_DIM; k0 += 16) {
#pragma unroll
        for (int r = 0; r < 4; ++r) {
            int e = r * 256 + tid;
            int mm = e >> 4, kk = e & 15;
            xs[kk][mm] = X[(size_t)(bm + mm) * K_DIM + k0 + kk];
            int code = CD[(size_t)(bn + mm) * K_DIM + k0 + kk];
            ws[kk][mm] = G[(bn + mm) * 8 + code];
        }
        __syncthreads();
#pragma unroll
        for (int kk = 0; kk < 16; ++kk)
#pragma unroll
            for (int i = 0; i < 4; ++i)
#pragma unroll
                for (int j = 0; j < 4; ++j)
                    acc[i][j] += xs[kk][tm * 4 + i] * ws[kk][tn * 4 + j];
        __syncthreads();
    }
#pragma unroll
    for (int i = 0; i < 4; ++i)
#pragma unroll
        for (int j = 0; j < 4; ++j)
            Y[(size_t)(bm + tm * 4 + i) * N_DIM + bn + tn * 4 + j] = acc[i][j];
}

extern "C" void kernel_launch(void* const* d_in, const int* in_sizes, int n_in,
                              void* d_out, int out_size, void* d_ws, size_t ws_size,
                              hipStream_t stream) {
    const float* x = (const float*)d_in[0];
    const float* qg = (const float*)d_in[1];
    const int* wc = (const int*)d_in[2];
    float* y = (float*)d_out;

    const size_t xb_elems = (size_t)M_DIM * K_DIM;
    const size_t wb_elems = (size_t)N_DIM * K_DIM;
    const size_t need = (xb_elems + wb_elems) * sizeof(ushort);

    if (ws_size >= need) {
        ushort* xb = (ushort*)d_ws;
        ushort* wb = xb + xb_elems;
        const int n4 = (int)(xb_elems / 4);
        hipLaunchKernelGGL(cvt_x, dim3(2048), dim3(256), 0, stream,
                           (const float4*)x, (ushort4*)xb, n4);
        hipLaunchKernelGGL(dequant, dim3(N_DIM), dim3(256), 0, stream, wc, qg, wb);
        const int nwg = (M_DIM / 256) * (N_DIM / 256);   // 512
        hipLaunchKernelGGL(gemm8, dim3(nwg), dim3(512), 0, stream,
                           xb, wb, y);
    } else {
        hipLaunchKernelGGL(fb_gemm, dim3(N_DIM / 64, M_DIM / 64), dim3(256), 0, stream,
                           x, qg, wc, y);
    }
}

// Round 6
// 287.965 us; speedup vs baseline: 2.3121x; 1.0103x over previous
//
#include <hip/hip_runtime.h>

// Sub4BitLinear: y = X[M,K] @ W[N,K]^T, M=8192 N=4096 K=4096
// (1) x f32->bf16, (2) dequant codes->bf16 W, (3) 256x256 8-phase MFMA GEMM.

#define M_DIM 8192
#define N_DIM 4096
#define K_DIM 4096
#define BK 64
#define NKT (K_DIM / BK)   // 64 K-tiles

typedef __attribute__((ext_vector_type(8))) short short8;
typedef __attribute__((ext_vector_type(4))) float f32x4;

#define AS1 __attribute__((address_space(1)))
#define AS3 __attribute__((address_space(3)))

__device__ __forceinline__ unsigned short f2bf(float f) {
    unsigned int u = __builtin_bit_cast(unsigned int, f);
    u += 0x7fffu + ((u >> 16) & 1u);
    return (unsigned short)(u >> 16);
}

__device__ __forceinline__ void gl_lds16(const void* g, void* l) {
    __builtin_amdgcn_global_load_lds((const AS1 void*)g, (AS3 void*)l, 16, 0, 0);
}

// ---------------- kernel 1: x f32 -> bf16 ----------------
__global__ __launch_bounds__(256) void cvt_x(const float4* __restrict__ X,
                                             ushort4* __restrict__ O, int n4) {
    int stride = gridDim.x * blockDim.x;
    for (int i = blockIdx.x * blockDim.x + threadIdx.x; i < n4; i += stride) {
        float4 v = X[i];
        ushort4 o;
        o.x = f2bf(v.x); o.y = f2bf(v.y); o.z = f2bf(v.z); o.w = f2bf(v.w);
        O[i] = o;
    }
}

// ---------------- kernel 2: dequant codes -> bf16 W ----------------
__global__ __launch_bounds__(256) void dequant(const int* __restrict__ CD,
                                               const float* __restrict__ G,
                                               ushort* __restrict__ W) {
    const int o = blockIdx.x;
    __shared__ ushort gs[8];
    if (threadIdx.x < 8) gs[threadIdx.x] = f2bf(G[o * 8 + threadIdx.x]);
    __syncthreads();
    const int4* cp = (const int4*)(CD + (size_t)o * K_DIM);
    ushort4* wp = (ushort4*)(W + (size_t)o * K_DIM);
#pragma unroll
    for (int r = 0; r < 4; ++r) {
        int idx = r * 256 + threadIdx.x;
        int4 c = cp[idx];
        ushort4 w;
        w.x = gs[c.x]; w.y = gs[c.y]; w.z = gs[c.z]; w.w = gs[c.w];
        wp[idx] = w;
    }
}

// ---------------- kernel 3: 256x256 8-phase bf16 MFMA GEMM ----------------
// 512 threads = 8 waves (2M x 4N); per-wave output 128x64 = acc[8][4] frags.
// LDS: [buf][half][128 x 64] A and B, XOR-swizzled (elem ^= (row&7)<<3).
// No blanket lgkmcnt(0): ds_reads are plain loads, so the compiler emits
// counted lgkm waits per consuming MFMA -> read drain overlaps MFMA within
// the phase. Race-safe: every phase's reads feed that phase's MFMA, so the
// data dep drains them before the phase-end barrier, and all overwriting
// STGs are >=1 phase later. Cross-phase motion blocked by PH_END fences.
__global__ __launch_bounds__(512, 2) void gemm8(const ushort* __restrict__ A,
                                                const ushort* __restrict__ B,
                                                float* __restrict__ C) {
    __shared__ ushort As[2][2][128 * 64];
    __shared__ ushort Bs[2][2][128 * 64];

    const int tid = threadIdx.x;
    const int lane = tid & 63;
    const int wid = tid >> 6;
    const int wm = wid >> 2;        // 0..1: wave's M half of the 256 tile
    const int wn = wid & 3;         // 0..3: wave's N slice
    const int bh = wn >> 1;         // B half-buffer

    // XCD-bijective block swizzle (nwg = 512, %8 == 0)
    int wg = blockIdx.x;
    wg = (wg & 7) * (gridDim.x >> 3) + (wg >> 3);
    const int ntn = N_DIM / 256;    // 16
    const int bm = (wg / ntn) * 256;
    const int bn = (wg % ntn) * 256;

    // fragment read lane constants:
    // elem = quad_off(static) + offk{ks};  offk = fr*64 + ((ks*32+fkc)^swz)
    const int fr = lane & 15;
    const int fkc = (lane >> 4) << 3;           // 0,8,16,24
    const int swz = (fr & 7) << 3;
    const int offk0 = fr * 64 + (fkc ^ (swz & 24)) + (swz & 32);
    const int offk1 = offk0 ^ 32;
    const int bwoff = (wn & 1) * 4096;          // B wave row-base (elements)

    // staging: chunk c = tid; row=c>>3 (+64 for 2nd instr), slot=(c&7)^(row&7)
    const int row0 = tid >> 3;                  // 0..63
    const int sl = (((tid & 7) ^ (row0 & 7)) << 3);

#define STG(GP, RB, KT, LD) do {                                                   \
        const int ks_ = (((KT) < NKT) ? (KT) : 0) * BK;                            \
        gl_lds16((GP) + (size_t)((RB) + row0) * K_DIM + ks_ + sl,                  \
                 (LD) + wid * 512);                                                \
        gl_lds16((GP) + (size_t)((RB) + row0 + 64) * K_DIM + ks_ + sl,             \
                 (LD) + 4096 + wid * 512);                                         \
    } while (0)

#define RD_A(B_, MH_)                                                              \
    _Pragma("unroll") for (int m = 0; m < 4; ++m) {                                \
        fa[(MH_) * 4 + m][0] = *(const short8*)&As[B_][wm][(MH_) * 4096 + m * 1024 + offk0]; \
        fa[(MH_) * 4 + m][1] = *(const short8*)&As[B_][wm][(MH_) * 4096 + m * 1024 + offk1]; \
    }

#define RD_B(B_, NH_)                                                              \
    _Pragma("unroll") for (int n = 0; n < 2; ++n) {                                \
        fb[(NH_) * 2 + n][0] = *(const short8*)&Bs[B_][bh][bwoff + (NH_) * 2048 + n * 1024 + offk0]; \
        fb[(NH_) * 2 + n][1] = *(const short8*)&Bs[B_][bh][bwoff + (NH_) * 2048 + n * 1024 + offk1]; \
    }

// ks-outer: 8 independent accumulators between dependent MFMA pairs
#define MF(MH_, NH_)                                                               \
    _Pragma("unroll") for (int ks = 0; ks < 2; ++ks)                               \
    _Pragma("unroll") for (int m = 0; m < 4; ++m)                                  \
    _Pragma("unroll") for (int n = 0; n < 2; ++n)                                  \
        acc[(MH_) * 4 + m][(NH_) * 2 + n] = __builtin_amdgcn_mfma_f32_16x16x32_bf16( \
            fa[(MH_) * 4 + m][ks], fb[(NH_) * 2 + n][ks],                          \
            acc[(MH_) * 4 + m][(NH_) * 2 + n], 0, 0, 0);

#define PH_MID                                                                     \
    __builtin_amdgcn_s_barrier();                                                  \
    __builtin_amdgcn_s_setprio(1);

#define PH_END                                                                     \
    __builtin_amdgcn_s_setprio(0);                                                 \
    __builtin_amdgcn_sched_barrier(0);                                             \
    __builtin_amdgcn_s_barrier();

#define PH_ENDW                                                                    \
    __builtin_amdgcn_s_setprio(0);                                                 \
    __builtin_amdgcn_sched_barrier(0);                                             \
    asm volatile("s_waitcnt vmcnt(6)" ::: "memory");                               \
    __builtin_amdgcn_s_barrier();

    f32x4 acc[8][4] = {};
    short8 fa[8][2];
    short8 fb[4][2];

    // prologue: tile0 {A0,A1,B0,B1}; tile1 {B0,B1,A0} (steady-state FIFO).
    STG(A, bm,       0, &As[0][0][0]);
    STG(A, bm + 128, 0, &As[0][1][0]);
    STG(B, bn,       0, &Bs[0][0][0]);
    STG(B, bn + 128, 0, &Bs[0][1][0]);
    STG(B, bn,       1, &Bs[1][0][0]);
    STG(B, bn + 128, 1, &Bs[1][1][0]);
    STG(A, bm,       1, &As[1][0][0]);
    asm volatile("s_waitcnt vmcnt(6)" ::: "memory");
    __builtin_amdgcn_s_barrier();

    for (int j = 0; j < NKT / 2; ++j) {
        const int o = 2 * j + 1, e2 = 2 * j + 2, o2 = 2 * j + 3;
        // p1: read e.{A-h0, B-h0}; stage o.A1
        RD_A(0, 0) RD_B(0, 0)
        STG(A, bm + 128, o, &As[1][1][0]);
        PH_MID MF(0, 0) PH_END
        // p2: read e.B-h1; stage e2.B0
        RD_B(0, 1)
        STG(B, bn, e2, &Bs[0][0][0]);
        PH_MID MF(0, 1) PH_END
        // p3: read e.A-h1; stage e2.B1
        RD_A(0, 1)
        STG(B, bn + 128, e2, &Bs[0][1][0]);
        PH_MID MF(1, 0) PH_END
        // p4: stage e2.A0; vmcnt(6) -> tile o fully resident
        STG(A, bm, e2, &As[0][0][0]);
        PH_MID MF(1, 1) PH_ENDW
        // p5: read o.{A-h0, B-h0}; stage e2.A1
        RD_A(1, 0) RD_B(1, 0)
        STG(A, bm + 128, e2, &As[0][1][0]);
        PH_MID MF(0, 0) PH_END
        // p6: read o.B-h1; stage o2.B0
        RD_B(1, 1)
        STG(B, bn, o2, &Bs[1][0][0]);
        PH_MID MF(0, 1) PH_END
        // p7: read o.A-h1; stage o2.B1
        RD_A(1, 1)
        STG(B, bn + 128, o2, &Bs[1][1][0]);
        PH_MID MF(1, 0) PH_END
        // p8: stage o2.A0; vmcnt(6) -> tile e2 fully resident
        STG(A, bm, o2, &As[1][0][0]);
        PH_MID MF(1, 1) PH_ENDW
    }
    asm volatile("s_waitcnt vmcnt(0)" ::: "memory");

    // C-write: row = (lane>>4)*4 + r, col = lane&15 within each 16x16 frag
    const int crow0 = bm + wm * 128 + ((lane >> 4) << 2);
    const int ccol0 = bn + wn * 64 + (lane & 15);
#pragma unroll
    for (int mi = 0; mi < 8; ++mi)
#pragma unroll
        for (int ni = 0; ni < 4; ++ni)
#pragma unroll
            for (int r = 0; r < 4; ++r)
                C[(size_t)(crow0 + mi * 16 + r) * N_DIM + ccol0 + ni * 16] = acc[mi][ni][r];
}

// ---------------- fallback: tiled f32 GEMM with on-the-fly dequant ----------------
__global__ __launch_bounds__(256) void fb_gemm(const float* __restrict__ X,
                                               const float* __restrict__ G,
                                               const int* __restrict__ CD,
                                               float* __restrict__ Y) {
    __shared__ float xs[16][64];
    __shared__ float ws[16][64];
    const int bm = blockIdx.y << 6, bn = blockIdx.x << 6;
    const int tid = threadIdx.x;
    const int tn = tid & 15, tm = tid >> 4;
    float acc[4][4] = {};
    for (int k0 = 0; k0 < K_DIM; k0 += 16) {
#pragma unroll
        for (int r = 0; r < 4; ++r) {
            int e = r * 256 + tid;
            int mm = e >> 4, kk = e & 15;
            xs[kk][mm] = X[(size_t)(bm + mm) * K_DIM + k0 + kk];
            int code = CD[(size_t)(bn + mm) * K_DIM + k0 + kk];
            ws[kk][mm] = G[(bn + mm) * 8 + code];
        }
        __syncthreads();
#pragma unroll
        for (int kk = 0; kk < 16; ++kk)
#pragma unroll
            for (int i = 0; i < 4; ++i)
#pragma unroll
                for (int j = 0; j < 4; ++j)
                    acc[i][j] += xs[kk][tm * 4 + i] * ws[kk][tn * 4 + j];
        __syncthreads();
    }
#pragma unroll
    for (int i = 0; i < 4; ++i)
#pragma unroll
        for (int j = 0; j < 4; ++j)
            Y[(size_t)(bm + tm * 4 + i) * N_DIM + bn + tn * 4 + j] = acc[i][j];
}

extern "C" void kernel_launch(void* const* d_in, const int* in_sizes, int n_in,
                              void* d_out, int out_size, void* d_ws, size_t ws_size,
                              hipStream_t stream) {
    const float* x = (const float*)d_in[0];
    const float* qg = (const float*)d_in[1];
    const int* wc = (const int*)d_in[2];
    float* y = (float*)d_out;

    const size_t xb_elems = (size_t)M_DIM * K_DIM;
    const size_t wb_elems = (size_t)N_DIM * K_DIM;
    const size_t need = (xb_elems + wb_elems) * sizeof(ushort);

    if (ws_size >= need) {
        ushort* xb = (ushort*)d_ws;
        ushort* wb = xb + xb_elems;
        const int n4 = (int)(xb_elems / 4);
        hipLaunchKernelGGL(cvt_x, dim3(2048), dim3(256), 0, stream,
                           (const float4*)x, (ushort4*)xb, n4);
        hipLaunchKernelGGL(dequant, dim3(N_DIM), dim3(256), 0, stream, wc, qg, wb);
        const int nwg = (M_DIM / 256) * (N_DIM / 256);   // 512
        hipLaunchKernelGGL(gemm8, dim3(nwg), dim3(512), 0, stream,
                           xb, wb, y);
    } else {
        hipLaunchKernelGGL(fb_gemm, dim3(N_DIM / 64, M_DIM / 64), dim3(256), 0, stream,
                           x, qg, wc, y);
    }
}

// Round 7
// 280.317 us; speedup vs baseline: 2.3752x; 1.0273x over previous
//
#include <hip/hip_runtime.h>

// Sub4BitLinear: y = X[M,K] @ W[N,K]^T, M=8192 N=4096 K=4096
// (1) x f32->bf16, (2) dequant codes->bf16 W, (3) 256x256 8-phase MFMA GEMM.

#define M_DIM 8192
#define N_DIM 4096
#define K_DIM 4096
#define BK 64
#define NKT (K_DIM / BK)   // 64 K-tiles

typedef __attribute__((ext_vector_type(8))) short short8;
typedef __attribute__((ext_vector_type(4))) float f32x4;

#define AS1 __attribute__((address_space(1)))
#define AS3 __attribute__((address_space(3)))

__device__ __forceinline__ unsigned short f2bf(float f) {
    unsigned int u = __builtin_bit_cast(unsigned int, f);
    u += 0x7fffu + ((u >> 16) & 1u);
    return (unsigned short)(u >> 16);
}

__device__ __forceinline__ void gl_lds16(const void* g, void* l) {
    __builtin_amdgcn_global_load_lds((const AS1 void*)g, (AS3 void*)l, 16, 0, 0);
}

// ---------------- kernel 1: x f32 -> bf16 ----------------
__global__ __launch_bounds__(256) void cvt_x(const float4* __restrict__ X,
                                             ushort4* __restrict__ O, int n4) {
    int stride = gridDim.x * blockDim.x;
    for (int i = blockIdx.x * blockDim.x + threadIdx.x; i < n4; i += stride) {
        float4 v = X[i];
        ushort4 o;
        o.x = f2bf(v.x); o.y = f2bf(v.y); o.z = f2bf(v.z); o.w = f2bf(v.w);
        O[i] = o;
    }
}

// ---------------- kernel 2: dequant codes -> bf16 W ----------------
__global__ __launch_bounds__(256) void dequant(const int* __restrict__ CD,
                                               const float* __restrict__ G,
                                               ushort* __restrict__ W) {
    const int o = blockIdx.x;
    __shared__ ushort gs[8];
    if (threadIdx.x < 8) gs[threadIdx.x] = f2bf(G[o * 8 + threadIdx.x]);
    __syncthreads();
    const int4* cp = (const int4*)(CD + (size_t)o * K_DIM);
    ushort4* wp = (ushort4*)(W + (size_t)o * K_DIM);
#pragma unroll
    for (int r = 0; r < 4; ++r) {
        int idx = r * 256 + threadIdx.x;
        int4 c = cp[idx];
        ushort4 w;
        w.x = gs[c.x]; w.y = gs[c.y]; w.z = gs[c.z]; w.w = gs[c.w];
        wp[idx] = w;
    }
}

// ---------------- kernel 3: 256x256 8-phase bf16 MFMA GEMM ----------------
// 512 threads = 8 waves (2M x 4N); per-wave output 128x64 = acc[8][4] frags.
// LDS: [buf][half][128 x 64] A and B, XOR-swizzled (elem ^= (row&7)<<3).
// ONE barrier per phase (at phase end). Audit: every STG's target buffer was
// last read >=2 phase-end barriers earlier; staged tiles are published by
// vmcnt(6)+barrier at p4/p8 before first read; no read touches an in-flight
// DMA target. Removing the mid-phase barrier lets one wave's read-issue
// window overlap its SIMD-neighbor's MFMA burst (we have 1 block/CU, so
// cross-block overlap cannot fill the bubble).
__global__ __launch_bounds__(512, 2) void gemm8(const ushort* __restrict__ A,
                                                const ushort* __restrict__ B,
                                                float* __restrict__ C) {
    __shared__ ushort As[2][2][128 * 64];
    __shared__ ushort Bs[2][2][128 * 64];

    const int tid = threadIdx.x;
    const int lane = tid & 63;
    const int wid = tid >> 6;
    const int wm = wid >> 2;        // 0..1: wave's M half of the 256 tile
    const int wn = wid & 3;         // 0..3: wave's N slice
    const int bh = wn >> 1;         // B half-buffer

    // XCD-bijective block swizzle (nwg = 512, %8 == 0)
    int wg = blockIdx.x;
    wg = (wg & 7) * (gridDim.x >> 3) + (wg >> 3);
    const int ntn = N_DIM / 256;    // 16
    const int bm = (wg / ntn) * 256;
    const int bn = (wg % ntn) * 256;

    // fragment read lane constants:
    // elem = quad_off(static) + offk{ks};  offk = fr*64 + ((ks*32+fkc)^swz)
    const int fr = lane & 15;
    const int fkc = (lane >> 4) << 3;           // 0,8,16,24
    const int swz = (fr & 7) << 3;
    const int offk0 = fr * 64 + (fkc ^ (swz & 24)) + (swz & 32);
    const int offk1 = offk0 ^ 32;
    const int bwoff = (wn & 1) * 4096;          // B wave row-base (elements)

    // staging: chunk c = tid; row=c>>3 (+64 for 2nd instr), slot=(c&7)^(row&7)
    const int row0 = tid >> 3;                  // 0..63
    const int sl = (((tid & 7) ^ (row0 & 7)) << 3);

#define STG(GP, RB, KT, LD) do {                                                   \
        const int ks_ = (((KT) < NKT) ? (KT) : 0) * BK;                            \
        gl_lds16((GP) + (size_t)((RB) + row0) * K_DIM + ks_ + sl,                  \
                 (LD) + wid * 512);                                                \
        gl_lds16((GP) + (size_t)((RB) + row0 + 64) * K_DIM + ks_ + sl,             \
                 (LD) + 4096 + wid * 512);                                         \
    } while (0)

#define RD_A(B_, MH_)                                                              \
    _Pragma("unroll") for (int m = 0; m < 4; ++m) {                                \
        fa[(MH_) * 4 + m][0] = *(const short8*)&As[B_][wm][(MH_) * 4096 + m * 1024 + offk0]; \
        fa[(MH_) * 4 + m][1] = *(const short8*)&As[B_][wm][(MH_) * 4096 + m * 1024 + offk1]; \
    }

#define RD_B(B_, NH_)                                                              \
    _Pragma("unroll") for (int n = 0; n < 2; ++n) {                                \
        fb[(NH_) * 2 + n][0] = *(const short8*)&Bs[B_][bh][bwoff + (NH_) * 2048 + n * 1024 + offk0]; \
        fb[(NH_) * 2 + n][1] = *(const short8*)&Bs[B_][bh][bwoff + (NH_) * 2048 + n * 1024 + offk1]; \
    }

// ks-outer: 8 independent accumulators between dependent MFMA pairs
#define MF(MH_, NH_)                                                               \
    _Pragma("unroll") for (int ks = 0; ks < 2; ++ks)                               \
    _Pragma("unroll") for (int m = 0; m < 4; ++m)                                  \
    _Pragma("unroll") for (int n = 0; n < 2; ++n)                                  \
        acc[(MH_) * 4 + m][(NH_) * 2 + n] = __builtin_amdgcn_mfma_f32_16x16x32_bf16( \
            fa[(MH_) * 4 + m][ks], fb[(NH_) * 2 + n][ks],                          \
            acc[(MH_) * 4 + m][(NH_) * 2 + n], 0, 0, 0);

#define PH_MID                                                                     \
    __builtin_amdgcn_s_setprio(1);

#define PH_END                                                                     \
    __builtin_amdgcn_s_setprio(0);                                                 \
    __builtin_amdgcn_sched_barrier(0);                                             \
    __builtin_amdgcn_s_barrier();

#define PH_ENDW                                                                    \
    __builtin_amdgcn_s_setprio(0);                                                 \
    __builtin_amdgcn_sched_barrier(0);                                             \
    asm volatile("s_waitcnt vmcnt(6)" ::: "memory");                               \
    __builtin_amdgcn_s_barrier();

    f32x4 acc[8][4] = {};
    short8 fa[8][2];
    short8 fb[4][2];

    // prologue: tile0 {A0,A1,B0,B1}; tile1 {B0,B1,A0} (steady-state FIFO).
    STG(A, bm,       0, &As[0][0][0]);
    STG(A, bm + 128, 0, &As[0][1][0]);
    STG(B, bn,       0, &Bs[0][0][0]);
    STG(B, bn + 128, 0, &Bs[0][1][0]);
    STG(B, bn,       1, &Bs[1][0][0]);
    STG(B, bn + 128, 1, &Bs[1][1][0]);
    STG(A, bm,       1, &As[1][0][0]);
    asm volatile("s_waitcnt vmcnt(6)" ::: "memory");
    __builtin_amdgcn_s_barrier();

    for (int j = 0; j < NKT / 2; ++j) {
        const int o = 2 * j + 1, e2 = 2 * j + 2, o2 = 2 * j + 3;
        // p1: read e.{A-h0, B-h0}; stage o.A1
        RD_A(0, 0) RD_B(0, 0)
        STG(A, bm + 128, o, &As[1][1][0]);
        PH_MID MF(0, 0) PH_END
        // p2: read e.B-h1; stage e2.B0
        RD_B(0, 1)
        STG(B, bn, e2, &Bs[0][0][0]);
        PH_MID MF(0, 1) PH_END
        // p3: read e.A-h1; stage e2.B1
        RD_A(0, 1)
        STG(B, bn + 128, e2, &Bs[0][1][0]);
        PH_MID MF(1, 0) PH_END
        // p4: stage e2.A0; vmcnt(6) -> tile o fully resident
        STG(A, bm, e2, &As[0][0][0]);
        PH_MID MF(1, 1) PH_ENDW
        // p5: read o.{A-h0, B-h0}; stage e2.A1
        RD_A(1, 0) RD_B(1, 0)
        STG(A, bm + 128, e2, &As[0][1][0]);
        PH_MID MF(0, 0) PH_END
        // p6: read o.B-h1; stage o2.B0
        RD_B(1, 1)
        STG(B, bn, o2, &Bs[1][0][0]);
        PH_MID MF(0, 1) PH_END
        // p7: read o.A-h1; stage o2.B1
        RD_A(1, 1)
        STG(B, bn + 128, o2, &Bs[1][1][0]);
        PH_MID MF(1, 0) PH_END
        // p8: stage o2.A0; vmcnt(6) -> tile e2 fully resident
        STG(A, bm, o2, &As[1][0][0]);
        PH_MID MF(1, 1) PH_ENDW
    }
    asm volatile("s_waitcnt vmcnt(0)" ::: "memory");

    // C-write: row = (lane>>4)*4 + r, col = lane&15 within each 16x16 frag
    const int crow0 = bm + wm * 128 + ((lane >> 4) << 2);
    const int ccol0 = bn + wn * 64 + (lane & 15);
#pragma unroll
    for (int mi = 0; mi < 8; ++mi)
#pragma unroll
        for (int ni = 0; ni < 4; ++ni)
#pragma unroll
            for (int r = 0; r < 4; ++r)
                C[(size_t)(crow0 + mi * 16 + r) * N_DIM + ccol0 + ni * 16] = acc[mi][ni][r];
}

// ---------------- fallback: tiled f32 GEMM with on-the-fly dequant ----------------
__global__ __launch_bounds__(256) void fb_gemm(const float* __restrict__ X,
                                               const float* __restrict__ G,
                                               const int* __restrict__ CD,
                                               float* __restrict__ Y) {
    __shared__ float xs[16][64];
    __shared__ float ws[16][64];
    const int bm = blockIdx.y << 6, bn = blockIdx.x << 6;
    const int tid = threadIdx.x;
    const int tn = tid & 15, tm = tid >> 4;
    float acc[4][4] = {};
    for (int k0 = 0; k0 < K_DIM; k0 += 16) {
#pragma unroll
        for (int r = 0; r < 4; ++r) {
            int e = r * 256 + tid;
            int mm = e >> 4, kk = e & 15;
            xs[kk][mm] = X[(size_t)(bm + mm) * K_DIM + k0 + kk];
            int code = CD[(size_t)(bn + mm) * K_DIM + k0 + kk];
            ws[kk][mm] = G[(bn + mm) * 8 + code];
        }
        __syncthreads();
#pragma unroll
        for (int kk = 0; kk < 16; ++kk)
#pragma unroll
            for (int i = 0; i < 4; ++i)
#pragma unroll
                for (int j = 0; j < 4; ++j)
                    acc[i][j] += xs[kk][tm * 4 + i] * ws[kk][tn * 4 + j];
        __syncthreads();
    }
#pragma unroll
    for (int i = 0; i < 4; ++i)
#pragma unroll
        for (int j = 0; j < 4; ++j)
            Y[(size_t)(bm + tm * 4 + i) * N_DIM + bn + tn * 4 + j] = acc[i][j];
}

extern "C" void kernel_launch(void* const* d_in, const int* in_sizes, int n_in,
                              void* d_out, int out_size, void* d_ws, size_t ws_size,
                              hipStream_t stream) {
    const float* x = (const float*)d_in[0];
    const float* qg = (const float*)d_in[1];
    const int* wc = (const int*)d_in[2];
    float* y = (float*)d_out;

    const size_t xb_elems = (size_t)M_DIM * K_DIM;
    const size_t wb_elems = (size_t)N_DIM * K_DIM;
    const size_t need = (xb_elems + wb_elems) * sizeof(ushort);

    if (ws_size >= need) {
        ushort* xb = (ushort*)d_ws;
        ushort* wb = xb + xb_elems;
        const int n4 = (int)(xb_elems / 4);
        hipLaunchKernelGGL(cvt_x, dim3(2048), dim3(256), 0, stream,
                           (const float4*)x, (ushort4*)xb, n4);
        hipLaunchKernelGGL(dequant, dim3(N_DIM), dim3(256), 0, stream, wc, qg, wb);
        const int nwg = (M_DIM / 256) * (N_DIM / 256);   // 512
        hipLaunchKernelGGL(gemm8, dim3(nwg), dim3(512), 0, stream,
                           xb, wb, y);
    } else {
        hipLaunchKernelGGL(fb_gemm, dim3(N_DIM / 64, M_DIM / 64), dim3(256), 0, stream,
                           x, qg, wc, y);
    }
}